// Round 3
// baseline (137283.484 us; speedup 1.0000x reference)
//
#include <hip/hip_runtime.h>

// CRSDBlock: 2-layer leaky reservoir RNN.
//   r_t = (1-a)*r_{t-1} + a*tanh(x_t@Wxr + h_{t-1}@Whr)
//   h_t = tanh(x_t@Wxh + h_{t-1}@Whh + r_t@Wrh)
// B=32, T=1024, D=R=1024, LAYERS=2, alpha=0.1
//
// Round 3: same as round 2 (split-bf16 hi+lo, 3-term MFMA) with the
// vector-element reference-binding compile error fixed (splitbf returns a
// struct; assign elements explicitly).

#define D_DIM 1024
#define T_DIM 1024
#define B_DIM 32
#define XROW ((size_t)T_DIM * D_DIM)   // row stride of x / out: 1048576
#define KT_N 32                        // K tiles (1024/32)
#define NT_N 64                        // N tiles (1024/16)

typedef __attribute__((ext_vector_type(8))) short short8;
typedef __attribute__((ext_vector_type(4))) float f32x4;

__device__ __forceinline__ unsigned short f2bf(float f) {
    unsigned int u = __float_as_uint(f);
    unsigned int r = u + 0x7FFFu + ((u >> 16) & 1u);  // round-nearest-even
    return (unsigned short)(r >> 16);
}
__device__ __forceinline__ float bf2f(unsigned short h) {
    return __uint_as_float(((unsigned int)h) << 16);
}
struct BfPair { short hi, lo; };
// Split one float into hi/lo bf16.
__device__ __forceinline__ BfPair splitbf(float f) {
    BfPair p;
    unsigned short h = f2bf(f);
    p.hi = (short)h;
    p.lo = (short)f2bf(f - bf2f(h));
    return p;
}

// Load 8 contiguous fp32 -> hi/lo bf16 frags.
__device__ __forceinline__ void ldfrag_split(const float* __restrict__ p,
                                             short8& hi, short8& lo) {
    f32x4 a = *(const f32x4*)p;
    f32x4 b = *(const f32x4*)(p + 4);
#pragma unroll
    for (int j = 0; j < 4; ++j) {
        BfPair s = splitbf(a[j]);
        hi[j] = s.hi; lo[j] = s.lo;
    }
#pragma unroll
    for (int j = 0; j < 4; ++j) {
        BfPair s = splitbf(b[j]);
        hi[4 + j] = s.hi; lo[4 + j] = s.lo;
    }
}

// Pack one [1024,1024] fp32 weight (K-major) into MFMA B-frag tiles, hi+lo:
// layout [kt][nt][lane] of 8 bf16 (16B) each; lane: quad=lane>>4, col=lane&15;
// element j = W[kt*32 + quad*8 + j][nt*16 + col].
__global__ __launch_bounds__(256) void pack_w_kernel(
        const float* __restrict__ W, short* __restrict__ Ph,
        short* __restrict__ Pl) {
    int tid  = blockIdx.x * 256 + threadIdx.x;   // 0..131071
    int lane = tid & 63;
    int tile = tid >> 6;                         // 0..2047
    int nt = tile & 63;
    int kt = tile >> 6;
    int quad = lane >> 4, col = lane & 15;
    int k0 = kt * 32 + quad * 8;
    int n  = nt * 16 + col;
    short8 oh, ol;
#pragma unroll
    for (int j = 0; j < 8; ++j) {
        BfPair s = splitbf(W[(size_t)(k0 + j) * D_DIM + n]);
        oh[j] = s.hi; ol[j] = s.lo;
    }
    ((short8*)Ph)[tid] = oh;
    ((short8*)Pl)[tid] = ol;
}

// 3-term split-bf16 MFMA accumulate: acc += (ah+al) @ (bh+bl), drop al*bl.
__device__ __forceinline__ f32x4 mfma3(short8 ah, short8 al, short8 bh,
                                       short8 bl, f32x4 acc) {
    acc = __builtin_amdgcn_mfma_f32_16x16x32_bf16(ah, bh, acc, 0, 0, 0);
    acc = __builtin_amdgcn_mfma_f32_16x16x32_bf16(al, bh, acc, 0, 0, 0);
    acc = __builtin_amdgcn_mfma_f32_16x16x32_bf16(ah, bl, acc, 0, 0, 0);
    return acc;
}

// Phase 1: 32 blocks x 256 = 128 waves. Waves 0-63 (group 0): S1 -> r update.
// Waves 64-127 (group 1): P = x@Wxh + h@Whh.
__global__ __launch_bounds__(256) void phase1_kernel(
        const float* __restrict__ xt,     // x_t base (row stride XROW)
        const short* __restrict__ hbh,    // h_{t-1} hi bf16 [32,1024]
        const short* __restrict__ hbl,    // h_{t-1} lo bf16
        const short* __restrict__ Wxr_h, const short* __restrict__ Wxr_l,
        const short* __restrict__ Whr_h, const short* __restrict__ Whr_l,
        const short* __restrict__ Wxh_h, const short* __restrict__ Wxh_l,
        const short* __restrict__ Whh_h, const short* __restrict__ Whh_l,
        float* __restrict__ r_f32, short* __restrict__ r_bh,
        short* __restrict__ r_bl, float* __restrict__ P) {
    int tid   = blockIdx.x * 256 + threadIdx.x;
    int wave  = tid >> 6;          // 0..127
    int lane  = threadIdx.x & 63;
    int group = wave >> 6;         // 0 -> S1(r), 1 -> S2(P)
    int nt    = wave & 63;
    int n0    = nt * 16;
    int quad = lane >> 4, col = lane & 15;

    const short8* WAh = (const short8*)(group ? Wxh_h : Wxr_h);  // x-part
    const short8* WAl = (const short8*)(group ? Wxh_l : Wxr_l);
    const short8* WBh = (const short8*)(group ? Whh_h : Whr_h);  // h-part
    const short8* WBl = (const short8*)(group ? Whh_l : Whr_l);

    f32x4 acc0 = {0.f, 0.f, 0.f, 0.f};
    f32x4 acc1 = {0.f, 0.f, 0.f, 0.f};

    for (int kt = 0; kt < KT_N; ++kt) {
        int k = kt * 32 + quad * 8;
        short8 ax0h, ax0l, ax1h, ax1l;
        ldfrag_split(xt + (size_t)col * XROW + k, ax0h, ax0l);
        ldfrag_split(xt + (size_t)(col + 16) * XROW + k, ax1h, ax1l);
        short8 ah0h = *(const short8*)(hbh + col * D_DIM + k);
        short8 ah0l = *(const short8*)(hbl + col * D_DIM + k);
        short8 ah1h = *(const short8*)(hbh + (col + 16) * D_DIM + k);
        short8 ah1l = *(const short8*)(hbl + (col + 16) * D_DIM + k);
        int wi = (kt * NT_N + nt) * 64 + lane;
        short8 wah = WAh[wi], wal = WAl[wi];
        short8 wbh = WBh[wi], wbl = WBl[wi];
        acc0 = mfma3(ax0h, ax0l, wah, wal, acc0);
        acc0 = mfma3(ah0h, ah0l, wbh, wbl, acc0);
        acc1 = mfma3(ax1h, ax1l, wah, wal, acc1);
        acc1 = mfma3(ah1h, ah1l, wbh, wbl, acc1);
    }

    if (group == 0) {
#pragma unroll
        for (int tile = 0; tile < 2; ++tile) {
            f32x4 acc = tile ? acc1 : acc0;
#pragma unroll
            for (int i = 0; i < 4; ++i) {
                int b = tile * 16 + quad * 4 + i;
                int idx = b * D_DIM + n0 + col;
                float rn = 0.9f * r_f32[idx] + 0.1f * tanhf(acc[i]);
                r_f32[idx] = rn;
                BfPair s = splitbf(rn);
                r_bh[idx] = s.hi;
                r_bl[idx] = s.lo;
            }
        }
    } else {
#pragma unroll
        for (int tile = 0; tile < 2; ++tile) {
            f32x4 acc = tile ? acc1 : acc0;
#pragma unroll
            for (int i = 0; i < 4; ++i) {
                int b = tile * 16 + quad * 4 + i;
                P[b * D_DIM + n0 + col] = acc[i];
            }
        }
    }
}

// Phase 2: 16 blocks x 256 = 64 waves. h = tanh(P + r_new@Wrh).
__global__ __launch_bounds__(256) void phase2_kernel(
        const short* __restrict__ rbh, const short* __restrict__ rbl,
        const short* __restrict__ Wrh_h, const short* __restrict__ Wrh_l,
        const float* __restrict__ P,
        float* __restrict__ out_t,      // out + t*D (row stride XROW)
        short* __restrict__ h_bh, short* __restrict__ h_bl) {
    int tid  = blockIdx.x * 256 + threadIdx.x;
    int wave = tid >> 6;               // 0..63
    int lane = threadIdx.x & 63;
    int nt = wave;
    int n0 = nt * 16;
    int quad = lane >> 4, col = lane & 15;

    const short8* Wh = (const short8*)Wrh_h;
    const short8* Wl = (const short8*)Wrh_l;
    f32x4 acc0 = {0.f, 0.f, 0.f, 0.f};
    f32x4 acc1 = {0.f, 0.f, 0.f, 0.f};

    for (int kt = 0; kt < KT_N; ++kt) {
        int k = kt * 32 + quad * 8;
        short8 a0h = *(const short8*)(rbh + col * D_DIM + k);
        short8 a0l = *(const short8*)(rbl + col * D_DIM + k);
        short8 a1h = *(const short8*)(rbh + (col + 16) * D_DIM + k);
        short8 a1l = *(const short8*)(rbl + (col + 16) * D_DIM + k);
        int wi = (kt * NT_N + nt) * 64 + lane;
        short8 wh = Wh[wi], wl = Wl[wi];
        acc0 = mfma3(a0h, a0l, wh, wl, acc0);
        acc1 = mfma3(a1h, a1l, wh, wl, acc1);
    }

#pragma unroll
    for (int tile = 0; tile < 2; ++tile) {
        f32x4 acc = tile ? acc1 : acc0;
#pragma unroll
        for (int i = 0; i < 4; ++i) {
            int b = tile * 16 + quad * 4 + i;
            int n = n0 + col;
            float hn = tanhf(P[b * D_DIM + n] + acc[i]);
            out_t[(size_t)b * XROW + n] = hn;
            BfPair s = splitbf(hn);
            h_bh[b * D_DIM + n] = s.hi;
            h_bl[b * D_DIM + n] = s.lo;
        }
    }
}

extern "C" void kernel_launch(void* const* d_in, const int* in_sizes, int n_in,
                              void* d_out, int out_size, void* d_ws, size_t ws_size,
                              hipStream_t stream) {
    const float* x_seq = (const float*)d_in[0];
    // d_in[1..5]: W_xh, W_hh, W_rh, W_xr, W_hr, each [2,1024,1024] fp32
    float* out = (float*)d_out;

    const size_t WSZ = (size_t)D_DIM * D_DIM;  // elements per matrix

    // ws layout: 10 matrices x (hi+lo) bf16 = 40 MB, then small states.
    auto pwHi = [&](int l, int wi) {
        return (short*)d_ws + ((size_t)(l * 5 + wi)) * 2 * WSZ;
    };
    auto pwLo = [&](int l, int wi) {
        return (short*)d_ws + ((size_t)(l * 5 + wi)) * 2 * WSZ + WSZ;
    };
    char* sp = (char*)d_ws + 20 * WSZ * sizeof(short);
    const size_t SB = (size_t)B_DIM * D_DIM;
    short* h0h = (short*)sp; sp += SB * sizeof(short);
    short* h0l = (short*)sp; sp += SB * sizeof(short);
    short* h1h = (short*)sp; sp += SB * sizeof(short);
    short* h1l = (short*)sp; sp += SB * sizeof(short);
    short* rbh = (short*)sp; sp += SB * sizeof(short);
    short* rbl = (short*)sp; sp += SB * sizeof(short);
    float* rf32 = (float*)sp; sp += SB * sizeof(float);
    float* P    = (float*)sp; sp += SB * sizeof(float);

    // Pack all 10 weight matrices (fp32 -> MFMA-tiled hi/lo bf16). Input
    // order: wi 0=W_xh 1=W_hh 2=W_rh 3=W_xr 4=W_hr.
    for (int l = 0; l < 2; ++l)
        for (int wi = 0; wi < 5; ++wi)
            pack_w_kernel<<<512, 256, 0, stream>>>(
                (const float*)d_in[1 + wi] + (size_t)l * WSZ,
                pwHi(l, wi), pwLo(l, wi));

    for (int l = 0; l < 2; ++l) {
        const float* xb = (l == 0) ? x_seq : out;   // layer 2 in-place on d_out
        (void)hipMemsetAsync(h0h, 0, SB * sizeof(short), stream);
        (void)hipMemsetAsync(h0l, 0, SB * sizeof(short), stream);
        (void)hipMemsetAsync(rf32, 0, SB * sizeof(float), stream);
        const short *Wxh_h = pwHi(l, 0), *Wxh_l = pwLo(l, 0);
        const short *Whh_h = pwHi(l, 1), *Whh_l = pwLo(l, 1);
        const short *Wrh_h = pwHi(l, 2), *Wrh_l = pwLo(l, 2);
        const short *Wxr_h = pwHi(l, 3), *Wxr_l = pwLo(l, 3);
        const short *Whr_h = pwHi(l, 4), *Whr_l = pwLo(l, 4);
        for (int t = 0; t < T_DIM; ++t) {
            const short* hbh = (t & 1) ? h1h : h0h;
            const short* hbl = (t & 1) ? h1l : h0l;
            short* hnh       = (t & 1) ? h0h : h1h;
            short* hnl       = (t & 1) ? h0l : h1l;
            phase1_kernel<<<32, 256, 0, stream>>>(
                xb + (size_t)t * D_DIM, hbh, hbl,
                Wxr_h, Wxr_l, Whr_h, Whr_l, Wxh_h, Wxh_l, Whh_h, Whh_l,
                rf32, rbh, rbl, P);
            phase2_kernel<<<16, 256, 0, stream>>>(
                rbh, rbl, Wrh_h, Wrh_l, P,
                out + (size_t)t * D_DIM, hnh, hnl);
        }
    }
}